// Round 5
// baseline (13.283 us; speedup 1.0000x reference)
//
#include <hip/hip_runtime.h>
#include <hip/hip_bf16.h>
#include <math.h>

// Problem constants
#define NB 8
#define NP 1024
#define ND 4
#define NTILES 32            // i-tiles per batch (32 rows each)
#define ITILE 32
#define BLOCKT 1024          // 32 i-rows x 32 j-streams
#define NSTREAM 32

#define INV_SQRT_2PI 0.3989422804014327f
#define RK 0.282095f
// pilot = 1.0592 * std * n^(-1/(4+d)) ; n=1024,d=4 -> 1024^(-0.125) = 2^-1.25
#define N_POW (0.42044820762685725f)

// ws layout (floats):
//   ws[b*32]                      : per-batch ticket (uint), NEVER reset.
//                                   Any 32 consecutive values contain exactly one
//                                   ==31 (mod 32), and 2^32 % 32 == 0, so the
//                                   last-block election works from any start value.
//   ws[256 + (b*32+tile)*4 + d]   : s2 half-sum partials (atomicExch'd every call)
#define WS_TICK_STRIDE 32
#define WS_PARTIAL 256

__global__ __launch_bounds__(1024) void bw_fused_kernel(const float* __restrict__ p,
                                                        float* __restrict__ ws,
                                                        float* __restrict__ out) {
    const int tile = blockIdx.x; // 0..NTILES-1
    const int b = blockIdx.y;    // 0..NB-1

    __shared__ float4 u[NP];     // RAW particles (never rescaled), 16 KB
    __shared__ float red[16][8];
    __shared__ float ipilS[4];
    __shared__ float pilS[4];
    __shared__ int lastS;

    const int wave = threadIdx.x >> 6;
    const int lane = threadIdx.x & 63;

    // ---- Phase A: load particles (1 float4/thread), per-batch stats ----
    const float4* pb = (const float4*)(p + (size_t)b * NP * ND);
    float4 v = pb[threadIdx.x];
    u[threadIdx.x] = v;

    float vals[8] = {v.x, v.y, v.z, v.w,
                     v.x * v.x, v.y * v.y, v.z * v.z, v.w * v.w};
#pragma unroll
    for (int off = 32; off > 0; off >>= 1) {
#pragma unroll
        for (int k = 0; k < 8; ++k) vals[k] += __shfl_down(vals[k], off, 64);
    }
    if (lane == 0) {
#pragma unroll
        for (int k = 0; k < 8; ++k) red[wave][k] = vals[k];
    }
    __syncthreads();
    if (threadIdx.x < ND) {
        int d = threadIdx.x;
        float sum = 0.f, sumsq = 0.f;
#pragma unroll
        for (int w = 0; w < 16; ++w) { sum += red[w][d]; sumsq += red[w][4 + d]; }
        float var = (sumsq - sum * sum / (float)NP) / (float)(NP - 1); // ddof=1
        float pilot = 1.0592f * sqrtf(var) * N_POW;
        ipilS[d] = 1.0f / pilot;
        pilS[d] = pilot;
    }
    __syncthreads();

    // ---- Phase B: symmetric pair loop (scale folded into fma) ----
    // Circular offsets o = 1..512 (o==512 half-weighted): each unordered
    // off-diagonal pair counted exactly once. s2_total = 2*acc - NP (diagonal).
    // s3 term is exactly 0 by antisymmetry -> not computed.
    // dx_d = (pj_d - pi_d) * ip_d = fma(pj_d, ip_d, -pi_d*ip_d)
    const int il = threadIdx.x & (ITILE - 1);
    const int js = threadIdx.x >> 5;          // 0..31: offset stream
    const int i = tile * ITILE + il;
    const float4 ip = make_float4(ipilS[0], ipilS[1], ipilS[2], ipilS[3]);
    const float4 ur = u[i];
    const float4 uis = make_float4(ur.x * ip.x, ur.y * ip.y, ur.z * ip.z, ur.w * ip.w);

    float t0 = 0.f, t1 = 0.f, t2 = 0.f, t3 = 0.f;

#pragma unroll
    for (int k2 = 0; k2 < 15; ++k2) {
        int o = 1 + js + (k2 << 5);      // 1..480 (all <= 480+31=511... max 448+31+1=480)
        int j = (i + o) & (NP - 1);
        float4 uj = u[j];
        float dxx = fmaf(uj.x, ip.x, -uis.x);
        float dxy = fmaf(uj.y, ip.y, -uis.y);
        float dxz = fmaf(uj.z, ip.z, -uis.z);
        float dxw = fmaf(uj.w, ip.w, -uis.w);
        float x2x = dxx * dxx, x2y = dxy * dxy, x2z = dxz * dxz, x2w = dxw * dxw;
        float r2 = x2x + x2y + x2z + x2w;
        float kf = __expf(-0.5f * r2);
        t0 = fmaf(kf, x2x - 1.0f, t0);
        t1 = fmaf(kf, x2y - 1.0f, t1);
        t2 = fmaf(kf, x2z - 1.0f, t2);
        t3 = fmaf(kf, x2w - 1.0f, t3);
    }
    { // peeled last iteration: o = 481+js (== 512 only for js==31, half weight)
        int o = 481 + js;
        int j = (i + o) & (NP - 1);
        float4 uj = u[j];
        float dxx = fmaf(uj.x, ip.x, -uis.x);
        float dxy = fmaf(uj.y, ip.y, -uis.y);
        float dxz = fmaf(uj.z, ip.z, -uis.z);
        float dxw = fmaf(uj.w, ip.w, -uis.w);
        float x2x = dxx * dxx, x2y = dxy * dxy, x2z = dxz * dxz, x2w = dxw * dxw;
        float r2 = x2x + x2y + x2z + x2w;
        float kf = __expf(-0.5f * r2) * ((o == 512) ? 0.5f : 1.0f);
        t0 = fmaf(kf, x2x - 1.0f, t0);
        t1 = fmaf(kf, x2y - 1.0f, t1);
        t2 = fmaf(kf, x2z - 1.0f, t2);
        t3 = fmaf(kf, x2w - 1.0f, t3);
    }

    float v4[4] = {t0, t1, t2, t3};
#pragma unroll
    for (int off = 32; off > 0; off >>= 1) {
#pragma unroll
        for (int k = 0; k < 4; ++k) v4[k] += __shfl_down(v4[k], off, 64);
    }
    if (lane == 0) {
#pragma unroll
        for (int k = 0; k < 4; ++k) red[wave][k] = v4[k];
    }
    __syncthreads();

    // ---- Phase C: publish partial, per-batch ticket ----
    if (threadIdx.x < 4) {
        float acc = 0.f;
#pragma unroll
        for (int w = 0; w < 16; ++w) acc += red[w][threadIdx.x];
        // relaxed agent-scope exchange: executes at the coherence point,
        // no L2 writeback (unlike __threadfence)
        __hip_atomic_exchange(&ws[WS_PARTIAL + (b * NTILES + tile) * 4 + threadIdx.x],
                              acc, __ATOMIC_RELAXED, __HIP_MEMORY_SCOPE_AGENT);
    }
    // All 4 publishing lanes are in wave 0: wave-level vmcnt(0) orders the
    // exchanges before the ticket RMW below. Harmless in other waves.
    asm volatile("s_waitcnt vmcnt(0)" ::: "memory");
    if (threadIdx.x == 0) {
        unsigned* tick = (unsigned*)ws + b * WS_TICK_STRIDE;
        unsigned t = __hip_atomic_fetch_add(tick, 1u,
                                            __ATOMIC_RELAXED, __HIP_MEMORY_SCOPE_AGENT);
        lastS = ((t & (NTILES - 1)) == (NTILES - 1)) ? 1 : 0;
    }
    __syncthreads();
    if (!lastS) return;

    // ---- Phase D: this block is last for batch b -> finalize out[b][:] ----
    // Read partials via +0.0f RMW (coherent even if local L2 holds stale
    // lines). Fixed-order summation -> deterministic output.
    float pv = 0.f;
    if (threadIdx.x < 128) {
        int tl = threadIdx.x >> 2, d = threadIdx.x & 3;
        pv = __hip_atomic_fetch_add(&ws[WS_PARTIAL + (b * NTILES + tl) * 4 + d], 0.0f,
                                    __ATOMIC_RELAXED, __HIP_MEMORY_SCOPE_AGENT);
    }
    __syncthreads(); // red[] reuse below
    // waves 0..1 hold tiles 0..15 / 16..31; shfl offsets 32,16,8,4 = tile strides 8,4,2,1
    if (threadIdx.x < 128) {
#pragma unroll
        for (int off = 32; off >= 4; off >>= 1) pv += __shfl_down(pv, off, 64);
        if (lane < 4) red[wave][lane] = pv;
    }
    __syncthreads();
    if (threadIdx.x < 4) {
        int d = threadIdx.x;
        float acc = red[0][d] + red[1][d];
        float s2tot = 2.0f * acc - (float)NP; // diagonal: -1 per i

        float pil = pilS[d];
        float p2 = pil * pil;
        float p5 = p2 * p2 * pil;
        const float denom = (float)NP * (float)(NP - 1);

        float I2 = s2tot * INV_SQRT_2PI / (p5 * denom);
        float J1 = RK / I2;              // MU2 = 1
        float base = J1 / (float)NP;
        // s3 == 0 by antisymmetry -> J2 = 0 -> bandwidth2 = 0
        float ab = fabsf(base);
        float sg = (base > 0.f) ? 1.0f : ((base < 0.f) ? -1.0f : 0.0f);
        out[b * ND + d] = sg * powf(ab, 0.2f);
    }
}

extern "C" void kernel_launch(void* const* d_in, const int* in_sizes, int n_in,
                              void* d_out, int out_size, void* d_ws, size_t ws_size,
                              hipStream_t stream) {
    const float* particles = (const float*)d_in[0];
    // d_in[1] (weights) is unused by the reference
    float* out = (float*)d_out;
    float* ws = (float*)d_ws;

    bw_fused_kernel<<<dim3(NTILES, NB), dim3(BLOCKT), 0, stream>>>(particles, ws, out);
}

// Round 6
// 12.360 us; speedup vs baseline: 1.0746x; 1.0746x over previous
//
#include <hip/hip_runtime.h>
#include <hip/hip_bf16.h>
#include <math.h>

// Problem constants
#define NB 8
#define NP 1024
#define ND 4
#define NTILES 32            // i-tiles per batch (32 rows each)
#define ITILE 32
#define BLOCKT 512           // 32 i-rows x 16 j-streams

#define INV_SQRT_2PI 0.3989422804014327f
#define RK 0.282095f
// pilot = 1.0592 * std * n^(-1/(4+d)) ; n=1024,d=4 -> 1024^(-0.125) = 2^-1.25
#define N_POW (0.42044820762685725f)

// ws layout (floats):
//   ws[b*32]                      : per-batch ticket (uint), NEVER reset.
//                                   Any 32 consecutive values contain exactly one
//                                   ==31 (mod 32), and 2^32 % 32 == 0, so the
//                                   last-block election works from any start value.
//   ws[256 + (b*32+tile)*4 + d]   : s2 half-sum partials (atomicExch'd every call)
#define WS_TICK_STRIDE 32
#define WS_PARTIAL 256

__global__ __launch_bounds__(512) void bw_fused_kernel(const float* __restrict__ p,
                                                       float* __restrict__ ws,
                                                       float* __restrict__ out) {
    const int tile = blockIdx.x; // 0..NTILES-1
    const int b = blockIdx.y;    // 0..NB-1

    __shared__ float4 u[NP];     // RAW particles (never rescaled), 16 KB
    __shared__ float red[8][8];
    __shared__ float ipilS[4];
    __shared__ float pilS[4];
    __shared__ int lastS;

    const int wave = threadIdx.x >> 6;
    const int lane = threadIdx.x & 63;

    // ---- Phase A: load particles (2 float4/thread), per-batch stats ----
    const float4* pb = (const float4*)(p + (size_t)b * NP * ND);
    float s0 = 0.f, s1 = 0.f, s2a = 0.f, s3a = 0.f;
    float q0 = 0.f, q1 = 0.f, q2 = 0.f, q3 = 0.f;
    for (int i = threadIdx.x; i < NP; i += BLOCKT) {
        float4 v = pb[i];
        u[i] = v;
        s0 += v.x; s1 += v.y; s2a += v.z; s3a += v.w;
        q0 = fmaf(v.x, v.x, q0); q1 = fmaf(v.y, v.y, q1);
        q2 = fmaf(v.z, v.z, q2); q3 = fmaf(v.w, v.w, q3);
    }
    float vals[8] = {s0, s1, s2a, s3a, q0, q1, q2, q3};
#pragma unroll
    for (int off = 32; off > 0; off >>= 1) {
#pragma unroll
        for (int k = 0; k < 8; ++k) vals[k] += __shfl_down(vals[k], off, 64);
    }
    if (lane == 0) {
#pragma unroll
        for (int k = 0; k < 8; ++k) red[wave][k] = vals[k];
    }
    __syncthreads();
    if (threadIdx.x < ND) {
        int d = threadIdx.x;
        float sum = 0.f, sumsq = 0.f;
#pragma unroll
        for (int w = 0; w < 8; ++w) { sum += red[w][d]; sumsq += red[w][4 + d]; }
        float var = (sumsq - sum * sum / (float)NP) / (float)(NP - 1); // ddof=1
        float pilot = 1.0592f * sqrtf(var) * N_POW;
        ipilS[d] = 1.0f / pilot;
        pilS[d] = pilot;
    }
    __syncthreads();

    // ---- Phase B: symmetric pair loop (scale folded into fma; u[] stays raw) ----
    // Circular offsets o = 1..512 (o==512 half-weighted): each unordered
    // off-diagonal pair counted exactly once. s2_total = 2*acc - NP (diagonal).
    // s3 term is exactly 0 by antisymmetry -> not computed.
    // dx_d = (pj_d - pi_d) * ip_d = fma(pj_d, ip_d, -pi_d*ip_d)
    const int il = threadIdx.x & (ITILE - 1);
    const int js = threadIdx.x >> 5;          // 0..15: offset stream
    const int i = tile * ITILE + il;
    const float4 ip = make_float4(ipilS[0], ipilS[1], ipilS[2], ipilS[3]);
    const float4 ur = u[i];
    const float4 uis = make_float4(ur.x * ip.x, ur.y * ip.y, ur.z * ip.z, ur.w * ip.w);

    float t0 = 0.f, t1 = 0.f, t2 = 0.f, t3 = 0.f;

#pragma unroll 8
    for (int k2 = 0; k2 < 31; ++k2) {
        int o = 1 + js + (k2 << 4);      // 1..496+js  (all <= 511)
        int j = (i + o) & (NP - 1);
        float4 uj = u[j];
        float dxx = fmaf(uj.x, ip.x, -uis.x);
        float dxy = fmaf(uj.y, ip.y, -uis.y);
        float dxz = fmaf(uj.z, ip.z, -uis.z);
        float dxw = fmaf(uj.w, ip.w, -uis.w);
        float x2x = dxx * dxx, x2y = dxy * dxy, x2z = dxz * dxz, x2w = dxw * dxw;
        float r2 = x2x + x2y + x2z + x2w;
        float kf = __expf(-0.5f * r2);
        t0 = fmaf(kf, x2x - 1.0f, t0);
        t1 = fmaf(kf, x2y - 1.0f, t1);
        t2 = fmaf(kf, x2z - 1.0f, t2);
        t3 = fmaf(kf, x2w - 1.0f, t3);
    }
    { // peeled last iteration: o = 497+js (== 512 only for js==15, half weight)
        int o = 497 + js;
        int j = (i + o) & (NP - 1);
        float4 uj = u[j];
        float dxx = fmaf(uj.x, ip.x, -uis.x);
        float dxy = fmaf(uj.y, ip.y, -uis.y);
        float dxz = fmaf(uj.z, ip.z, -uis.z);
        float dxw = fmaf(uj.w, ip.w, -uis.w);
        float x2x = dxx * dxx, x2y = dxy * dxy, x2z = dxz * dxz, x2w = dxw * dxw;
        float r2 = x2x + x2y + x2z + x2w;
        float kf = __expf(-0.5f * r2) * ((o == 512) ? 0.5f : 1.0f);
        t0 = fmaf(kf, x2x - 1.0f, t0);
        t1 = fmaf(kf, x2y - 1.0f, t1);
        t2 = fmaf(kf, x2z - 1.0f, t2);
        t3 = fmaf(kf, x2w - 1.0f, t3);
    }

    float v4[4] = {t0, t1, t2, t3};
#pragma unroll
    for (int off = 32; off > 0; off >>= 1) {
#pragma unroll
        for (int k = 0; k < 4; ++k) v4[k] += __shfl_down(v4[k], off, 64);
    }
    if (lane == 0) {
#pragma unroll
        for (int k = 0; k < 4; ++k) red[wave][k] = v4[k];
    }
    __syncthreads();

    // ---- Phase C: publish partial, per-batch ticket ----
    if (threadIdx.x < 4) {
        float acc = 0.f;
#pragma unroll
        for (int w = 0; w < 8; ++w) acc += red[w][threadIdx.x];
        // relaxed agent-scope exchange: executes at the coherence point,
        // no L2 writeback (unlike __threadfence)
        __hip_atomic_exchange(&ws[WS_PARTIAL + (b * NTILES + tile) * 4 + threadIdx.x],
                              acc, __ATOMIC_RELAXED, __HIP_MEMORY_SCOPE_AGENT);
    }
    // All 4 publishing lanes are in wave 0: wave-level vmcnt(0) orders the
    // exchanges before the ticket RMW below. Harmless in other waves.
    asm volatile("s_waitcnt vmcnt(0)" ::: "memory");
    if (threadIdx.x == 0) {
        unsigned* tick = (unsigned*)ws + b * WS_TICK_STRIDE;
        unsigned t = __hip_atomic_fetch_add(tick, 1u,
                                            __ATOMIC_RELAXED, __HIP_MEMORY_SCOPE_AGENT);
        lastS = ((t & (NTILES - 1)) == (NTILES - 1)) ? 1 : 0;
    }
    __syncthreads();
    if (!lastS) return;

    // ---- Phase D: this block is last for batch b -> finalize out[b][:] ----
    // Read partials via +0.0f RMW (coherent even if local L2 holds stale
    // lines). Fixed-order summation -> deterministic output.
    float pv = 0.f;
    if (threadIdx.x < 128) {
        int tl = threadIdx.x >> 2, d = threadIdx.x & 3;
        pv = __hip_atomic_fetch_add(&ws[WS_PARTIAL + (b * NTILES + tl) * 4 + d], 0.0f,
                                    __ATOMIC_RELAXED, __HIP_MEMORY_SCOPE_AGENT);
    }
    __syncthreads(); // red[] reuse below
    // waves 0..1 hold tiles 0..15 / 16..31; shfl offsets 32,16,8,4 = tile strides 8,4,2,1
    if (threadIdx.x < 128) {
#pragma unroll
        for (int off = 32; off >= 4; off >>= 1) pv += __shfl_down(pv, off, 64);
        if (lane < 4) red[wave][lane] = pv;
    }
    __syncthreads();
    if (threadIdx.x < 4) {
        int d = threadIdx.x;
        float acc = red[0][d] + red[1][d];
        float s2tot = 2.0f * acc - (float)NP; // diagonal: -1 per i

        float pil = pilS[d];
        float p2 = pil * pil;
        float p5 = p2 * p2 * pil;
        const float denom = (float)NP * (float)(NP - 1);

        float I2 = s2tot * INV_SQRT_2PI / (p5 * denom);
        float J1 = RK / I2;              // MU2 = 1
        float base = J1 / (float)NP;
        // s3 == 0 by antisymmetry -> J2 = 0 -> bandwidth2 = 0
        float ab = fabsf(base);
        float sg = (base > 0.f) ? 1.0f : ((base < 0.f) ? -1.0f : 0.0f);
        out[b * ND + d] = sg * powf(ab, 0.2f);
    }
}

extern "C" void kernel_launch(void* const* d_in, const int* in_sizes, int n_in,
                              void* d_out, int out_size, void* d_ws, size_t ws_size,
                              hipStream_t stream) {
    const float* particles = (const float*)d_in[0];
    // d_in[1] (weights) is unused by the reference
    float* out = (float*)d_out;
    float* ws = (float*)d_ws;

    bw_fused_kernel<<<dim3(NTILES, NB), dim3(BLOCKT), 0, stream>>>(particles, ws, out);
}